// Round 2
// baseline (346.024 us; speedup 1.0000x reference)
//
#include <hip/hip_runtime.h>
#include <hip/hip_bf16.h>

constexpr int N = 10000;   // nodes
constexpr int D = 512;     // feature dim
constexpr int E = 160000;  // edges
constexpr int L = 3;       // layers
constexpr float EPS = 1e-5f;

constexpr int NSHARD = 8;          // one feature shard per XCD
constexpr int SHCOL = D / NSHARD;  // 64 cols = 128 B per row-slice

typedef _Float16 half8 __attribute__((ext_vector_type(8)));
typedef _Float16 half2v __attribute__((ext_vector_type(2)));
typedef float floatx4 __attribute__((ext_vector_type(4)));

// async global->LDS, 16B per lane. LDS dest = wave-uniform base + lane*16.
__device__ __forceinline__ void glds16(const _Float16* g, _Float16* l) {
    __builtin_amdgcn_global_load_lds(
        (const __attribute__((address_space(1))) uint32_t*)(g),
        (__attribute__((address_space(3))) uint32_t*)(l),
        16, 0, 0);
}

// ---------------------------------------------------------------------------
// Mega setup: degrees + x fp32->f16 conversion + column stats + W transpose.
// ---------------------------------------------------------------------------
constexpr int DEG_BLOCKS  = (E + 255) / 256;   // 625
constexpr int CONV_BLOCKS = 100;               // 100 rows each
constexpr int TW_BLOCKS   = L * 256;           // 768 (32x32 tiles)
constexpr int MEGA_BLOCKS = DEG_BLOCKS + CONV_BLOCKS + TW_BLOCKS;

__global__ __launch_bounds__(256) void mega_setup(
    const int* __restrict__ src, const int* __restrict__ dst,
    const float* __restrict__ x, const float* __restrict__ W,
    int* __restrict__ out_deg, int* __restrict__ in_deg,
    _Float16* __restrict__ x16, float* __restrict__ stats0,
    _Float16* __restrict__ Wt) {
    __shared__ float tb[32][33];
    int bid = blockIdx.x;
    int tid = threadIdx.x;
    if (bid < DEG_BLOCKS) {
        int e = bid * 256 + tid;
        if (e < E) {
            atomicAdd(&out_deg[src[e]], 1);
            atomicAdd(&in_deg[dst[e]], 1);
        }
    } else if (bid < DEG_BLOCKS + CONV_BLOCKS) {
        int b = bid - DEG_BLOCKS;
        int r0 = b * 100;
        int r1 = r0 + 100; if (r1 > N) r1 = N;
        int c2 = tid * 2;
        float s0 = 0.f, s1 = 0.f, q0 = 0.f, q1 = 0.f;
        for (int r = r0; r < r1; ++r) {
            float2 v = *(const float2*)(x + (size_t)r * D + c2);
            s0 += v.x; q0 += v.x * v.x;
            s1 += v.y; q1 += v.y * v.y;
            half2v h; h[0] = (_Float16)v.x; h[1] = (_Float16)v.y;
            *(half2v*)(x16 + (size_t)r * D + c2) = h;
        }
        atomicAdd(&stats0[c2], s0);
        atomicAdd(&stats0[c2 + 1], s1);
        atomicAdd(&stats0[D + c2], q0);
        atomicAdd(&stats0[D + c2 + 1], q1);
    } else {
        int b = bid - DEG_BLOCKS - CONV_BLOCKS;  // 0..767
        int l = b >> 8;
        int t = b & 255;
        int k0 = (t >> 4) * 32, n0 = (t & 15) * 32;
        int tx = tid & 31, ty = tid >> 5;  // 32 x 8
        const float* Wl = W + (size_t)l * D * D;
        _Float16* Wtl = Wt + (size_t)l * D * D;
        for (int i = 0; i < 32; i += 8)
            tb[ty + i][tx] = Wl[(size_t)(k0 + ty + i) * D + n0 + tx];
        __syncthreads();
        for (int i = 0; i < 32; i += 8)
            Wtl[(size_t)(n0 + ty + i) * D + k0 + tx] = (_Float16)tb[tx][ty + i];
    }
}

// ---------------------------------------------------------------------------
// Single block: exclusive scan of in_deg -> off & cursor, plus both norms.
// ---------------------------------------------------------------------------
__global__ void scan_indeg(const int* __restrict__ in_deg,
                           const int* __restrict__ out_deg,
                           int* __restrict__ off, int* __restrict__ cursor,
                           float* __restrict__ src_norm, float* __restrict__ dst_norm) {
    __shared__ int lsum[1024];
    int t = threadIdx.x;
    const int chunk = (N + 1023) / 1024;
    int start = t * chunk;
    int end = start + chunk; if (end > N) end = N;
    int s = 0;
    for (int i = start; i < end; ++i) s += in_deg[i];
    lsum[t] = s;
    __syncthreads();
    for (int d = 1; d < 1024; d <<= 1) {
        int v = (t >= d) ? lsum[t - d] : 0;
        __syncthreads();
        lsum[t] += v;
        __syncthreads();
    }
    int excl = (t == 0) ? 0 : lsum[t - 1];
    for (int i = start; i < end; ++i) {
        off[i] = excl;
        cursor[i] = excl;
        excl += in_deg[i];
        int od = out_deg[i]; if (od < 1) od = 1;
        int id = in_deg[i];  if (id < 1) id = 1;
        src_norm[i] = rsqrtf((float)od);
        dst_norm[i] = rsqrtf((float)id);
    }
    if (t == 1023) off[N] = lsum[1023];
}

__global__ void csr_fill(const int* __restrict__ src, const int* __restrict__ dst,
                         int* __restrict__ cursor, int* __restrict__ csr_src) {
    int e = blockIdx.x * blockDim.x + threadIdx.x;
    if (e >= E) return;
    int d = dst[e];
    int pos = atomicAdd(&cursor[d], 1);
    csr_src[pos] = src[e];
}

// ---------------------------------------------------------------------------
// Fused BN + gather-aggregate, XCD-sharded over the feature dim.
// shard = bid%8 -> pinned to one XCD (HW maps dispatch index % 8 -> XCD),
// so each XCD's working set is a 10000 x 128B column slice = 1.28 MB (L2-fit).
// Wave = one dst node x one shard. Lanes 0-31 handle even edges, 32-63 odd;
// each lane owns 2 columns (one dword load per edge).
// ---------------------------------------------------------------------------
__global__ __launch_bounds__(256) void aggregate_bn_shard(
    const _Float16* __restrict__ x, const int* __restrict__ off,
    const int* __restrict__ csr_src, const float* __restrict__ src_norm,
    const float* __restrict__ dst_norm, const float* __restrict__ stats,
    const float* __restrict__ gamma, const float* __restrict__ beta,
    _Float16* __restrict__ agg) {
    int shard = blockIdx.x & 7;
    int blk   = blockIdx.x >> 3;
    int wave  = threadIdx.x >> 6;
    int wid   = blk * 4 + wave;          // dst node, exactly < N by grid sizing
    int lane  = threadIdx.x & 63;
    int half  = lane >> 5;               // edge parity
    int cl    = lane & 31;               // col-pair index
    int c0    = shard * SHCOL + cl * 2;  // two cols: c0, c0+1

    // BN coefficients for this lane's 2 columns
    const float invN = 1.0f / (float)N;
    float2 sv = *(const float2*)(stats + c0);
    float2 qv = *(const float2*)(stats + D + c0);
    float2 gm = *(const float2*)(gamma + c0);
    float2 bt = *(const float2*)(beta + c0);
    float mu0 = sv.x * invN, mu1 = sv.y * invN;
    float var0 = qv.x * invN - mu0 * mu0;
    float var1 = qv.y * invN - mu1 * mu1;
    float sc0 = gm.x * rsqrtf(var0 + EPS);
    float sc1 = gm.y * rsqrtf(var1 + EPS);
    float sh0 = bt.x - mu0 * sc0;
    float sh1 = bt.y - mu1 * sc1;

    int e0 = off[wid], e1 = off[wid + 1];
    const _Float16* xs = x + c0;
    float a0 = 0.f, a1 = 0.f, b0 = 0.f, b1 = 0.f, tA = 0.f, tB = 0.f;
    int e = e0 + half;
    // 2x unroll: two independent edge chains per lane
    for (; e + 2 < e1; e += 4) {
        int sA = csr_src[e];
        int sB = csr_src[e + 2];
        float nA = src_norm[sA];
        float nB = src_norm[sB];
        half2v vA = *(const half2v*)(xs + (size_t)sA * D);
        half2v vB = *(const half2v*)(xs + (size_t)sB * D);
        a0 += (float)vA[0] * nA; a1 += (float)vA[1] * nA; tA += nA;
        b0 += (float)vB[0] * nB; b1 += (float)vB[1] * nB; tB += nB;
    }
    for (; e < e1; e += 2) {
        int sA = csr_src[e];
        float nA = src_norm[sA];
        half2v vA = *(const half2v*)(xs + (size_t)sA * D);
        a0 += (float)vA[0] * nA; a1 += (float)vA[1] * nA; tA += nA;
    }
    a0 += b0; a1 += b1;
    float t = tA + tB;
    a0 += __shfl_xor(a0, 32);
    a1 += __shfl_xor(a1, 32);
    t  += __shfl_xor(t, 32);
    if (half == 0) {
        float dn = dst_norm[wid];
        half2v o;
        o[0] = (_Float16)(dn * (sc0 * a0 + sh0 * t));
        o[1] = (_Float16)(dn * (sc1 * a1 + sh1 * t));
        *(half2v*)(agg + (size_t)wid * D + c0) = o;
    }
}

// ---------------------------------------------------------------------------
// C = relu(A @ W + bias) via f16 MFMA.
// Tile 64(M) x 128(N), BK=64, block = 128 threads (2 waves).
// Each wave computes a 64x64 output (4x4 tiles of mfma_f32_16x16x32_f16) --
// identical fragment math to the verified 128x128 kernel.
// Double-buffered LDS, 2-phase pipeline (stage t+1 before computing t).
// LDS XOR chunk-swizzle: global source pre-swizzled (linear glds dest),
// same involution applied on ds_read -> b128 reads at the bank floor.
// ---------------------------------------------------------------------------
template <typename OutT, bool STATS>
__global__ __launch_bounds__(128) void mm_f16_relu(
    const _Float16* __restrict__ A, const _Float16* __restrict__ Bt,
    const float* __restrict__ bias, OutT* __restrict__ C, int M,
    float* __restrict__ stats) {
    __shared__ __align__(16) _Float16 As[2][64 * 64];    // 16 KB
    __shared__ __align__(16) _Float16 Bs[2][128 * 64];   // 32 KB
    const int tid  = threadIdx.x;
    const int wave = tid >> 6;
    const int lane = tid & 63;
    const int quad = lane >> 4;
    const int l16  = lane & 15;
    const int row0 = blockIdx.x * 64;
    const int col0 = blockIdx.y * 128;
    const int wn   = wave * 64;

    // staging lane map: 8 rows x 8 chunks of 16B per wave-glds (1 KB slab)
    const int srl = lane >> 3;          // row within slab 0..7
    const int sq  = lane & 7;           // dest chunk 0..7
    const int sqs = (sq ^ srl) * 8;     // pre-swizzled source col (f16 units)

    const _Float16* gA[4];
    const _Float16* gB[8];
#pragma unroll
    for (int j = 0; j < 4; ++j) {
        int ar = row0 + wave * 32 + j * 8 + srl;
        if (ar >= M) ar = M - 1;
        gA[j] = A + (size_t)ar * D + sqs;
    }
#pragma unroll
    for (int j = 0; j < 8; ++j) {
        int br = col0 + wave * 64 + j * 8 + srl;
        gB[j] = Bt + (size_t)br * D + sqs;
    }

    // read-side swizzled chunk offsets (f16 units); row&7 == l16&7 here
    const int l7 = l16 & 7;
    const int swz0 = (quad ^ l7) * 8;        // kk=0: chunk = quad
    const int swz1 = ((4 + quad) ^ l7) * 8;  // kk=1: chunk = 4+quad

    floatx4 acc[4][4] = {};

    auto stage = [&](int buf, int k0) {
        _Float16* as = As[buf] + (wave * 32) * 64;
        _Float16* bs = Bs[buf] + (wave * 64) * 64;
#pragma unroll
        for (int j = 0; j < 4; ++j)
            glds16(gA[j] + k0, as + j * 8 * 64);
#pragma unroll
        for (int j = 0; j < 8; ++j)
            glds16(gB[j] + k0, bs + j * 8 * 64);
    };

    stage(0, 0);
    __syncthreads();  // compiler drains vmcnt before barrier

    int cur = 0;
    for (int kt = 0; kt < 8; ++kt) {
        if (kt < 7) stage(cur ^ 1, (kt + 1) * 64);
        const _Float16* asb = As[cur];
        const _Float16* bsb = Bs[cur];
        half8 af0[4], af1[4], bf0[4], bf1[4];
#pragma unroll
        for (int i = 0; i < 4; ++i) {
            int r = i * 16 + l16;
            af0[i] = *(const half8*)(asb + r * 64 + swz0);
            af1[i] = *(const half8*)(asb + r * 64 + swz1);
        }
#pragma unroll
        for (int j = 0; j < 4; ++j) {
            int r = wn + j * 16 + l16;
            bf0[j] = *(const half8*)(bsb + r * 64 + swz0);
            bf1[j] = *(const half8*)(bsb + r * 64 + swz1);
        }
#pragma unroll
        for (int i = 0; i < 4; ++i)
#pragma unroll
            for (int j = 0; j < 4; ++j)
                acc[i][j] = __builtin_amdgcn_mfma_f32_16x16x32_f16(
                    af0[i], bf0[j], acc[i][j], 0, 0, 0);
#pragma unroll
        for (int i = 0; i < 4; ++i)
#pragma unroll
            for (int j = 0; j < 4; ++j)
                acc[i][j] = __builtin_amdgcn_mfma_f32_16x16x32_f16(
                    af1[i], bf1[j], acc[i][j], 0, 0, 0);
        __syncthreads();  // drains staged loads + joins waves
        cur ^= 1;
    }

    // epilogue: C/D layout col = lane&15, row = quad*4 + reg
    float s[4] = {}, q[4] = {};
#pragma unroll
    for (int i = 0; i < 4; ++i) {
#pragma unroll
        for (int r = 0; r < 4; ++r) {
            int row = row0 + i * 16 + quad * 4 + r;
            bool valid = row < M;
#pragma unroll
            for (int j = 0; j < 4; ++j) {
                int col = col0 + wn + j * 16 + l16;
                float v = acc[i][j][r] + bias[col];
                v = v > 0.f ? v : 0.f;
                if (valid) {
                    C[(size_t)row * D + col] = (OutT)v;
                    if (STATS) { s[j] += v; q[j] += v * v; }
                }
            }
        }
    }
    if (STATS) {
#pragma unroll
        for (int j = 0; j < 4; ++j) {
            float sv = s[j], qv = q[j];
            sv += __shfl_xor(sv, 16); sv += __shfl_xor(sv, 32);
            qv += __shfl_xor(qv, 16); qv += __shfl_xor(qv, 32);
            if (quad == 0) {
                int col = col0 + wn + j * 16 + l16;
                atomicAdd(&stats[col], sv);
                atomicAdd(&stats[D + col], qv);
            }
        }
    }
}

// ---------------------------------------------------------------------------
extern "C" void kernel_launch(void* const* d_in, const int* in_sizes, int n_in,
                              void* d_out, int out_size, void* d_ws, size_t ws_size,
                              hipStream_t stream) {
    const float* x_in  = (const float*)d_in[0];
    const int*   src   = (const int*)d_in[1];
    const int*   dst   = (const int*)d_in[2];
    const float* gamma = (const float*)d_in[3];
    const float* beta  = (const float*)d_in[4];
    const float* W     = (const float*)d_in[5];
    const float* b     = (const float*)d_in[6];
    float* out = (float*)d_out;

    // workspace carve-up (16B-aligned segments first)
    char* p = (char*)d_ws;
    _Float16* x16 = (_Float16*)p;  p += (size_t)N * D * 2;       // 10.24 MB
    _Float16* agg = (_Float16*)p;  p += (size_t)N * D * 2;       // 10.24 MB
    _Float16* Wt  = (_Float16*)p;  p += (size_t)L * D * D * 2;   // 1.57 MB
    float* src_norm = (float*)p;   p += (size_t)N * 4;
    float* dst_norm = (float*)p;   p += (size_t)N * 4;
    // contiguous zero-init region: out_deg, in_deg, stats0..2
    int* out_deg   = (int*)p;      p += (size_t)N * 4;
    int* in_deg    = (int*)p;      p += (size_t)N * 4;
    float* stats0  = (float*)p;    p += 2 * D * 4;
    float* stats1  = (float*)p;    p += 2 * D * 4;
    float* stats2  = (float*)p;    p += 2 * D * 4;
    int* csr_off   = (int*)p;      p += (size_t)(N + 1) * 4;
    int* cursor    = (int*)p;      p += (size_t)N * 4;
    int* csr_src   = (int*)p;      p += (size_t)E * 4;

    float* stats_in[3] = {stats0, stats1, stats2};

    // --- setup ---
    hipMemsetAsync(out_deg, 0, (2 * (size_t)N + 6 * D) * sizeof(int), stream);
    mega_setup<<<MEGA_BLOCKS, 256, 0, stream>>>(src, dst, x_in, W,
                                                out_deg, in_deg, x16, stats0, Wt);
    scan_indeg<<<1, 1024, 0, stream>>>(in_deg, out_deg, csr_off, cursor,
                                       src_norm, dst_norm);
    csr_fill<<<DEG_BLOCKS, 256, 0, stream>>>(src, dst, cursor, csr_src);

    dim3 mm_grid((N + 63) / 64, D / 128);                 // 157 x 4
    const int agg_blocks = NSHARD * ((N + 3) / 4);        // 8 x 2500 = 20000

    for (int l = 0; l < L; ++l) {
        const float* gl  = gamma + (size_t)l * D;
        const float* bl  = beta + (size_t)l * D;
        const _Float16* Wl = Wt + (size_t)l * D * D;
        const float* bil = b + (size_t)l * D;

        aggregate_bn_shard<<<agg_blocks, 256, 0, stream>>>(
            x16, csr_off, csr_src, src_norm, dst_norm, stats_in[l], gl, bl, agg);
        if (l == L - 1) {
            mm_f16_relu<float, false><<<mm_grid, 128, 0, stream>>>(
                agg, Wl, bil, out, N, nullptr);
        } else {
            mm_f16_relu<_Float16, true><<<mm_grid, 128, 0, stream>>>(
                agg, Wl, bil, x16, N, stats_in[l + 1]);
        }
    }
}

// Round 3
// 321.055 us; speedup vs baseline: 1.0778x; 1.0778x over previous
//
#include <hip/hip_runtime.h>
#include <hip/hip_bf16.h>

constexpr int N = 10000;   // nodes
constexpr int D = 512;     // feature dim
constexpr int E = 160000;  // edges
constexpr int L = 3;       // layers
constexpr float EPS = 1e-5f;

constexpr int NSH = 4;          // feature shards (XCD x sees shard x&3 only)
constexpr int SHC = D / NSH;    // 128 cols = 256 B per row-slice

typedef _Float16 half8 __attribute__((ext_vector_type(8)));
typedef _Float16 half2v __attribute__((ext_vector_type(2)));
typedef float floatx4 __attribute__((ext_vector_type(4)));

// async global->LDS, 16B per lane. LDS dest = wave-uniform base + lane*16.
__device__ __forceinline__ void glds16(const _Float16* g, _Float16* l) {
    __builtin_amdgcn_global_load_lds(
        (const __attribute__((address_space(1))) uint32_t*)(g),
        (__attribute__((address_space(3))) uint32_t*)(l),
        16, 0, 0);
}

// ---------------------------------------------------------------------------
// Mega setup: degrees + column stats of x + W transpose. (x16 conversion moved
// to csr_fill_conv, after src_norm exists, so rows can be pre-scaled.)
// ---------------------------------------------------------------------------
constexpr int DEG_BLOCKS  = (E + 255) / 256;   // 625
constexpr int STAT_BLOCKS = 500;               // 20 rows each
constexpr int TW_BLOCKS   = L * 256;           // 768 (32x32 tiles)
constexpr int MEGA_BLOCKS = DEG_BLOCKS + STAT_BLOCKS + TW_BLOCKS;

__global__ __launch_bounds__(256) void mega_setup(
    const int* __restrict__ src, const int* __restrict__ dst,
    const float* __restrict__ x, const float* __restrict__ W,
    int* __restrict__ out_deg, int* __restrict__ in_deg,
    float* __restrict__ stats0, _Float16* __restrict__ Wt) {
    __shared__ float tb[32][33];
    int bid = blockIdx.x;
    int tid = threadIdx.x;
    if (bid < DEG_BLOCKS) {
        int e = bid * 256 + tid;
        if (e < E) {
            atomicAdd(&out_deg[src[e]], 1);
            atomicAdd(&in_deg[dst[e]], 1);
        }
    } else if (bid < DEG_BLOCKS + STAT_BLOCKS) {
        int b = bid - DEG_BLOCKS;
        int r0 = b * 20;
        int r1 = r0 + 20; if (r1 > N) r1 = N;
        int c2 = tid * 2;
        float s0 = 0.f, s1 = 0.f, q0 = 0.f, q1 = 0.f;
        for (int r = r0; r < r1; ++r) {
            float2 v = *(const float2*)(x + (size_t)r * D + c2);
            s0 += v.x; q0 += v.x * v.x;
            s1 += v.y; q1 += v.y * v.y;
        }
        atomicAdd(&stats0[c2], s0);
        atomicAdd(&stats0[c2 + 1], s1);
        atomicAdd(&stats0[D + c2], q0);
        atomicAdd(&stats0[D + c2 + 1], q1);
    } else {
        int b = bid - DEG_BLOCKS - STAT_BLOCKS;  // 0..767
        int l = b >> 8;
        int t = b & 255;
        int k0 = (t >> 4) * 32, n0 = (t & 15) * 32;
        int tx = tid & 31, ty = tid >> 5;  // 32 x 8
        const float* Wl = W + (size_t)l * D * D;
        _Float16* Wtl = Wt + (size_t)l * D * D;
        for (int i = 0; i < 32; i += 8)
            tb[ty + i][tx] = Wl[(size_t)(k0 + ty + i) * D + n0 + tx];
        __syncthreads();
        for (int i = 0; i < 32; i += 8)
            Wtl[(size_t)(n0 + ty + i) * D + k0 + tx] = (_Float16)tb[tx][ty + i];
    }
}

// ---------------------------------------------------------------------------
// Single block: exclusive scan of in_deg -> off & cursor, plus both norms.
// ---------------------------------------------------------------------------
__global__ void scan_indeg(const int* __restrict__ in_deg,
                           const int* __restrict__ out_deg,
                           int* __restrict__ off, int* __restrict__ cursor,
                           float* __restrict__ src_norm, float* __restrict__ dst_norm) {
    __shared__ int lsum[1024];
    int t = threadIdx.x;
    const int chunk = (N + 1023) / 1024;
    int start = t * chunk;
    int end = start + chunk; if (end > N) end = N;
    int s = 0;
    for (int i = start; i < end; ++i) s += in_deg[i];
    lsum[t] = s;
    __syncthreads();
    for (int d = 1; d < 1024; d <<= 1) {
        int v = (t >= d) ? lsum[t - d] : 0;
        __syncthreads();
        lsum[t] += v;
        __syncthreads();
    }
    int excl = (t == 0) ? 0 : lsum[t - 1];
    for (int i = start; i < end; ++i) {
        off[i] = excl;
        cursor[i] = excl;
        excl += in_deg[i];
        int od = out_deg[i]; if (od < 1) od = 1;
        int id = in_deg[i];  if (id < 1) id = 1;
        src_norm[i] = rsqrtf((float)od);
        dst_norm[i] = rsqrtf((float)id);
    }
    if (t == 1023) off[N] = lsum[1023];
}

// ---------------------------------------------------------------------------
// csr fill + T[d] = sum(src_norm[src]) per dst, plus pre-scaled f16 convert:
// x16[r][:] = (f16)(x[r][:] * src_norm[r]).  Runs after scan_indeg.
// ---------------------------------------------------------------------------
constexpr int CONV_BLOCKS = 500;  // 20 rows each
__global__ __launch_bounds__(256) void csr_fill_conv(
    const int* __restrict__ src, const int* __restrict__ dst,
    const float* __restrict__ x, const float* __restrict__ src_norm,
    int* __restrict__ cursor, int* __restrict__ csr_src,
    float* __restrict__ T, _Float16* __restrict__ x16) {
    int bid = blockIdx.x;
    int tid = threadIdx.x;
    if (bid < DEG_BLOCKS) {
        int e = bid * 256 + tid;
        if (e < E) {
            int s = src[e], d = dst[e];
            int pos = atomicAdd(&cursor[d], 1);
            csr_src[pos] = s;
            atomicAdd(&T[d], src_norm[s]);
        }
    } else {
        int b = bid - DEG_BLOCKS;
        int r0 = b * 20;
        int r1 = r0 + 20; if (r1 > N) r1 = N;
        int c2 = tid * 2;
        for (int r = r0; r < r1; ++r) {
            float sn = src_norm[r];
            float2 v = *(const float2*)(x + (size_t)r * D + c2);
            half2v h;
            h[0] = (_Float16)(v.x * sn);
            h[1] = (_Float16)(v.y * sn);
            *(half2v*)(x16 + (size_t)r * D + c2) = h;
        }
    }
}

// ---------------------------------------------------------------------------
// Aggregate + BN, 4-way feature-sharded with 16B/lane payload.
// Wave = (node, shard of 128 cols). lane = (edge-slot e 0..3, chunk 0..15):
// one global_load_dwordx4 delivers 4 edges x 256B = 1KB.
// shard = bid&3 and XCD = bid%8  =>  XCD x only touches shard x&3:
// per-XCD working set = 10000 x 256B = 2.56MB <= 4MB L2.
// Rows are pre-scaled by src_norm, so no per-edge norm load; the BN-shift
// term uses the precomputed layer-invariant T[d].
// ---------------------------------------------------------------------------
__global__ __launch_bounds__(256) void aggregate4(
    const _Float16* __restrict__ xs, const int* __restrict__ off,
    const int* __restrict__ csr_src, const float* __restrict__ T,
    const float* __restrict__ dst_norm, const float* __restrict__ stats,
    const float* __restrict__ gamma, const float* __restrict__ beta,
    _Float16* __restrict__ agg) {
    int shard = blockIdx.x & 3;
    int wid = (blockIdx.x >> 2) * 4 + (threadIdx.x >> 6);  // < N by grid sizing
    int lane = threadIdx.x & 63;
    int eg = lane >> 4;   // edge slot 0..3
    int ch = lane & 15;   // 16B chunk
    int c0 = shard * SHC + ch * 8;

    int e0 = off[wid], e1 = off[wid + 1];
    const _Float16* xp = xs + c0;
    float a[8] = {}, b2[8] = {};
    int e = e0 + eg;
    // 2x unroll: two independent 1KB gathers in flight per wave
    for (; e + 4 < e1; e += 8) {
        int s0 = csr_src[e];
        int s1 = csr_src[e + 4];
        half8 v0 = *(const half8*)(xp + (size_t)s0 * D);
        half8 v1 = *(const half8*)(xp + (size_t)s1 * D);
#pragma unroll
        for (int k = 0; k < 8; ++k) { a[k] += (float)v0[k]; b2[k] += (float)v1[k]; }
    }
    if (e < e1) {
        int s0 = csr_src[e];
        half8 v0 = *(const half8*)(xp + (size_t)s0 * D);
#pragma unroll
        for (int k = 0; k < 8; ++k) a[k] += (float)v0[k];
    }
#pragma unroll
    for (int k = 0; k < 8; ++k) {
        a[k] += b2[k];
        a[k] += __shfl_xor(a[k], 16);
        a[k] += __shfl_xor(a[k], 32);
    }
    if (eg == 0) {
        float t = T[wid];
        float dn = dst_norm[wid];
        const float invN = 1.0f / (float)N;
        half8 o;
#pragma unroll
        for (int k = 0; k < 8; ++k) {
            int c = c0 + k;
            float mu = stats[c] * invN;
            float var = stats[D + c] * invN - mu * mu;
            float sc = gamma[c] * rsqrtf(var + EPS);
            float sh = beta[c] - mu * sc;
            o[k] = (_Float16)(dn * (sc * a[k] + sh * t));
        }
        *(half8*)(agg + (size_t)wid * D + c0) = o;
    }
}

// ---------------------------------------------------------------------------
// C = relu(A @ W + bias) via f16 MFMA with global_load_lds staging.
// (round-1 verified structure: 128x128 tile, BK=32, 4 waves)
// STATS variant additionally pre-scales the stored f16 value by src_norm[row]
// (stats accumulate the RAW value) so the next layer's aggregate needs no
// per-edge norm loads.
// ---------------------------------------------------------------------------
template <typename OutT, bool STATS>
__global__ __launch_bounds__(256) void mm_f16_relu(
    const _Float16* __restrict__ A, const _Float16* __restrict__ Bt,
    const float* __restrict__ bias, OutT* __restrict__ C, int M,
    float* __restrict__ stats, const float* __restrict__ src_norm) {
    __shared__ __align__(16) _Float16 As[128 * 32];
    __shared__ __align__(16) _Float16 Bs[128 * 32];
    const int tid  = threadIdx.x;
    const int wave = tid >> 6;
    const int lane = tid & 63;
    const int quad = lane >> 4;
    const int l16  = lane & 15;
    const int row0 = blockIdx.x * 128;
    const int col0 = blockIdx.y * 128;
    const int wm = (wave & 1) * 64;
    const int wn = (wave >> 1) * 64;
    const int sr = lane >> 2;
    const int sc = (lane & 3) * 8;

    int ar0 = row0 + wave * 32 + sr;
    int ar1 = ar0 + 16;
    if (ar0 >= M) ar0 = M - 1;
    if (ar1 >= M) ar1 = M - 1;
    const _Float16* gA0 = A + (size_t)ar0 * D + sc;
    const _Float16* gA1 = A + (size_t)ar1 * D + sc;
    const _Float16* gB0 = Bt + (size_t)(col0 + wave * 32 + sr) * D + sc;
    const _Float16* gB1 = Bt + (size_t)(col0 + wave * 32 + 16 + sr) * D + sc;
    _Float16* lA0 = As + (wave * 32) * 32;
    _Float16* lA1 = As + (wave * 32 + 16) * 32;
    _Float16* lB0 = Bs + (wave * 32) * 32;
    _Float16* lB1 = Bs + (wave * 32 + 16) * 32;

    floatx4 acc[4][4] = {};

    for (int k0 = 0; k0 < D; k0 += 32) {
        __syncthreads();
        glds16(gA0 + k0, lA0);
        glds16(gA1 + k0, lA1);
        glds16(gB0 + k0, lB0);
        glds16(gB1 + k0, lB1);
        __syncthreads();  // compiler inserts vmcnt(0) drain here
        half8 af[4], bf[4];
        for (int i = 0; i < 4; ++i)
            af[i] = *(const half8*)(As + (wm + i * 16 + l16) * 32 + quad * 8);
        for (int j = 0; j < 4; ++j)
            bf[j] = *(const half8*)(Bs + (wn + j * 16 + l16) * 32 + quad * 8);
        for (int i = 0; i < 4; ++i)
            for (int j = 0; j < 4; ++j)
                acc[i][j] = __builtin_amdgcn_mfma_f32_16x16x32_f16(
                    af[i], bf[j], acc[i][j], 0, 0, 0);
    }

    // epilogue: C/D layout col = lane&15, row = quad*4 + reg
    float s[4] = {}, q[4] = {};
    for (int i = 0; i < 4; ++i) {
        for (int r = 0; r < 4; ++r) {
            int row = row0 + wm + i * 16 + quad * 4 + r;
            bool valid = row < M;
            float sn = 1.0f;
            if (STATS && valid) sn = src_norm[row];
            for (int j = 0; j < 4; ++j) {
                int col = col0 + wn + j * 16 + l16;
                float v = acc[i][j][r] + bias[col];
                v = v > 0.f ? v : 0.f;
                if (valid) {
                    if (STATS) {
                        C[(size_t)row * D + col] = (OutT)(v * sn);
                        s[j] += v; q[j] += v * v;
                    } else {
                        C[(size_t)row * D + col] = (OutT)v;
                    }
                }
            }
        }
    }
    if (STATS) {
        for (int j = 0; j < 4; ++j) {
            float sv = s[j], qv = q[j];
            sv += __shfl_xor(sv, 16); sv += __shfl_xor(sv, 32);
            qv += __shfl_xor(qv, 16); qv += __shfl_xor(qv, 32);
            if (quad == 0) {
                int col = col0 + wn + j * 16 + l16;
                atomicAdd(&stats[col], sv);
                atomicAdd(&stats[D + col], qv);
            }
        }
    }
}

// ---------------------------------------------------------------------------
extern "C" void kernel_launch(void* const* d_in, const int* in_sizes, int n_in,
                              void* d_out, int out_size, void* d_ws, size_t ws_size,
                              hipStream_t stream) {
    const float* x_in  = (const float*)d_in[0];
    const int*   src   = (const int*)d_in[1];
    const int*   dst   = (const int*)d_in[2];
    const float* gamma = (const float*)d_in[3];
    const float* beta  = (const float*)d_in[4];
    const float* W     = (const float*)d_in[5];
    const float* b     = (const float*)d_in[6];
    float* out = (float*)d_out;

    // workspace carve-up (16B-aligned segments first)
    char* p = (char*)d_ws;
    _Float16* x16 = (_Float16*)p;  p += (size_t)N * D * 2;       // 10.24 MB
    _Float16* agg = (_Float16*)p;  p += (size_t)N * D * 2;       // 10.24 MB
    _Float16* Wt  = (_Float16*)p;  p += (size_t)L * D * D * 2;   // 1.57 MB
    float* src_norm = (float*)p;   p += (size_t)N * 4;
    float* dst_norm = (float*)p;   p += (size_t)N * 4;
    // contiguous zero-init region: out_deg, in_deg, stats0..2, T
    int* out_deg   = (int*)p;      p += (size_t)N * 4;
    int* in_deg    = (int*)p;      p += (size_t)N * 4;
    float* stats0  = (float*)p;    p += 2 * D * 4;
    float* stats1  = (float*)p;    p += 2 * D * 4;
    float* stats2  = (float*)p;    p += 2 * D * 4;
    float* T       = (float*)p;    p += (size_t)N * 4;
    int* csr_off   = (int*)p;      p += (size_t)(N + 1) * 4;
    int* cursor    = (int*)p;      p += (size_t)N * 4;
    int* csr_src   = (int*)p;      p += (size_t)E * 4;

    float* stats_in[3] = {stats0, stats1, stats2};

    // --- setup ---
    hipMemsetAsync(out_deg, 0, (3 * (size_t)N + 6 * D) * sizeof(int), stream);
    mega_setup<<<MEGA_BLOCKS, 256, 0, stream>>>(src, dst, x_in, W,
                                                out_deg, in_deg, stats0, Wt);
    scan_indeg<<<1, 1024, 0, stream>>>(in_deg, out_deg, csr_off, cursor,
                                       src_norm, dst_norm);
    csr_fill_conv<<<DEG_BLOCKS + CONV_BLOCKS, 256, 0, stream>>>(
        src, dst, x_in, src_norm, cursor, csr_src, T, x16);

    dim3 mm_grid((N + 127) / 128, D / 128);
    const int agg_blocks = NSH * ((N + 3) / 4);  // 4 x 2500 = 10000

    for (int l = 0; l < L; ++l) {
        const float* gl  = gamma + (size_t)l * D;
        const float* bl  = beta + (size_t)l * D;
        const _Float16* Wl = Wt + (size_t)l * D * D;
        const float* bil = b + (size_t)l * D;

        aggregate4<<<agg_blocks, 256, 0, stream>>>(
            x16, csr_off, csr_src, T, dst_norm, stats_in[l], gl, bl, agg);
        if (l == L - 1) {
            mm_f16_relu<float, false><<<mm_grid, 256, 0, stream>>>(
                agg, Wl, bil, out, N, nullptr, nullptr);
        } else {
            mm_f16_relu<_Float16, true><<<mm_grid, 256, 0, stream>>>(
                agg, Wl, bil, x16, N, stats_in[l + 1], src_norm);
        }
    }
}

// Round 4
// 302.943 us; speedup vs baseline: 1.1422x; 1.0598x over previous
//
#include <hip/hip_runtime.h>
#include <hip/hip_bf16.h>

constexpr int N = 10000;   // nodes
constexpr int D = 512;     // feature dim
constexpr int E = 160000;  // edges
constexpr int L = 3;       // layers
constexpr float EPS = 1e-5f;

typedef _Float16 half8 __attribute__((ext_vector_type(8)));
typedef _Float16 half2v __attribute__((ext_vector_type(2)));
typedef float floatx4 __attribute__((ext_vector_type(4)));

// async global->LDS, 16B per lane. LDS dest = wave-uniform base + lane*16.
__device__ __forceinline__ void glds16(const _Float16* g, _Float16* l) {
    __builtin_amdgcn_global_load_lds(
        (const __attribute__((address_space(1))) uint32_t*)(g),
        (__attribute__((address_space(3))) uint32_t*)(l),
        16, 0, 0);
}

// ---------------------------------------------------------------------------
// Mega setup: degrees + column stats of x + W transpose. (x16 conversion in
// csr_fill_conv, after out_deg exists, so rows can be pre-scaled.)
// ---------------------------------------------------------------------------
constexpr int DEG_BLOCKS  = (E + 255) / 256;   // 625
constexpr int STAT_BLOCKS = 500;               // 20 rows each
constexpr int TW_BLOCKS   = L * 256;           // 768 (32x32 tiles)
constexpr int MEGA_BLOCKS = DEG_BLOCKS + STAT_BLOCKS + TW_BLOCKS;

__global__ __launch_bounds__(256) void mega_setup(
    const int* __restrict__ src, const int* __restrict__ dst,
    const float* __restrict__ x, const float* __restrict__ W,
    int* __restrict__ out_deg, int* __restrict__ in_deg,
    float* __restrict__ stats0, _Float16* __restrict__ Wt) {
    __shared__ float tb[32][33];
    int bid = blockIdx.x;
    int tid = threadIdx.x;
    if (bid < DEG_BLOCKS) {
        int e = bid * 256 + tid;
        if (e < E) {
            atomicAdd(&out_deg[src[e]], 1);
            atomicAdd(&in_deg[dst[e]], 1);
        }
    } else if (bid < DEG_BLOCKS + STAT_BLOCKS) {
        int b = bid - DEG_BLOCKS;
        int r0 = b * 20;
        int r1 = r0 + 20; if (r1 > N) r1 = N;
        int c2 = tid * 2;
        float s0 = 0.f, s1 = 0.f, q0 = 0.f, q1 = 0.f;
        for (int r = r0; r < r1; ++r) {
            float2 v = *(const float2*)(x + (size_t)r * D + c2);
            s0 += v.x; q0 += v.x * v.x;
            s1 += v.y; q1 += v.y * v.y;
        }
        atomicAdd(&stats0[c2], s0);
        atomicAdd(&stats0[c2 + 1], s1);
        atomicAdd(&stats0[D + c2], q0);
        atomicAdd(&stats0[D + c2 + 1], q1);
    } else {
        int b = bid - DEG_BLOCKS - STAT_BLOCKS;  // 0..767
        int l = b >> 8;
        int t = b & 255;
        int k0 = (t >> 4) * 32, n0 = (t & 15) * 32;
        int tx = tid & 31, ty = tid >> 5;  // 32 x 8
        const float* Wl = W + (size_t)l * D * D;
        _Float16* Wtl = Wt + (size_t)l * D * D;
        for (int i = 0; i < 32; i += 8)
            tb[ty + i][tx] = Wl[(size_t)(k0 + ty + i) * D + n0 + tx];
        __syncthreads();
        for (int i = 0; i < 32; i += 8)
            Wtl[(size_t)(n0 + ty + i) * D + k0 + tx] = (_Float16)tb[tx][ty + i];
    }
}

// ---------------------------------------------------------------------------
// Single block: exclusive scan of in_deg -> off & cursor, plus both norms.
// ---------------------------------------------------------------------------
__global__ void scan_indeg(const int* __restrict__ in_deg,
                           const int* __restrict__ out_deg,
                           int* __restrict__ off, int* __restrict__ cursor,
                           float* __restrict__ src_norm, float* __restrict__ dst_norm) {
    __shared__ int lsum[1024];
    int t = threadIdx.x;
    const int chunk = (N + 1023) / 1024;
    int start = t * chunk;
    int end = start + chunk; if (end > N) end = N;
    int s = 0;
    for (int i = start; i < end; ++i) s += in_deg[i];
    lsum[t] = s;
    __syncthreads();
    for (int d = 1; d < 1024; d <<= 1) {
        int v = (t >= d) ? lsum[t - d] : 0;
        __syncthreads();
        lsum[t] += v;
        __syncthreads();
    }
    int excl = (t == 0) ? 0 : lsum[t - 1];
    for (int i = start; i < end; ++i) {
        off[i] = excl;
        cursor[i] = excl;
        excl += in_deg[i];
        int od = out_deg[i]; if (od < 1) od = 1;
        int id = in_deg[i];  if (id < 1) id = 1;
        src_norm[i] = rsqrtf((float)od);
        dst_norm[i] = rsqrtf((float)id);
    }
    if (t == 1023) off[N] = lsum[1023];
}

// ---------------------------------------------------------------------------
// csr fill + T[d] = sum(src_norm[src]) per dst, plus pre-scaled f16 convert:
// x16[r][:] = (f16)(x[r][:] * src_norm[r]).  Runs after scan_indeg.
// ---------------------------------------------------------------------------
constexpr int CONV_BLOCKS = 500;  // 20 rows each
__global__ __launch_bounds__(256) void csr_fill_conv(
    const int* __restrict__ src, const int* __restrict__ dst,
    const float* __restrict__ x, const float* __restrict__ src_norm,
    int* __restrict__ cursor, int* __restrict__ csr_src,
    float* __restrict__ T, _Float16* __restrict__ x16) {
    int bid = blockIdx.x;
    int tid = threadIdx.x;
    if (bid < DEG_BLOCKS) {
        int e = bid * 256 + tid;
        if (e < E) {
            int s = src[e], d = dst[e];
            int pos = atomicAdd(&cursor[d], 1);
            csr_src[pos] = s;
            atomicAdd(&T[d], src_norm[s]);
        }
    } else {
        int b = bid - DEG_BLOCKS;
        int r0 = b * 20;
        int r1 = r0 + 20; if (r1 > N) r1 = N;
        int c2 = tid * 2;
        for (int r = r0; r < r1; ++r) {
            float sn = src_norm[r];
            float2 v = *(const float2*)(x + (size_t)r * D + c2);
            half2v h;
            h[0] = (_Float16)(v.x * sn);
            h[1] = (_Float16)(v.y * sn);
            *(half2v*)(x16 + (size_t)r * D + c2) = h;
        }
    }
}

// ---------------------------------------------------------------------------
// Aggregate + BN. One wave per node, full 512-col rows (64 lanes x 8 cols,
// one dwordx4 = 1KB row per load  -- the round-1-proven access pattern).
// Rows are PRE-SCALED by src_norm, so the inner loop is idx -> payload only
// (no per-edge norm gather).  BN coefs computed after the loop (low loop VGPR).
// 6-edge unroll: 6 independent 1KB loads in flight per wave.
// ---------------------------------------------------------------------------
__global__ __launch_bounds__(256) void aggregate_pre(
    const _Float16* __restrict__ xs, const int* __restrict__ off,
    const int* __restrict__ csr_src, const float* __restrict__ T,
    const float* __restrict__ dst_norm, const float* __restrict__ stats,
    const float* __restrict__ gamma, const float* __restrict__ beta,
    _Float16* __restrict__ agg) {
    int wid = blockIdx.x * 4 + (threadIdx.x >> 6);  // grid covers exactly N
    int lane = threadIdx.x & 63;
    int c0 = lane * 8;
    const _Float16* xp = xs + c0;

    // wave-uniform edge range -> SGPR (enables scalar scheduling)
    int e0 = __builtin_amdgcn_readfirstlane(off[wid]);
    int e1 = __builtin_amdgcn_readfirstlane(off[wid + 1]);

    float a[8] = {}, b2[8] = {};
    int e = e0;
    for (; e + 6 <= e1; e += 6) {
        int s0 = csr_src[e];
        int s1 = csr_src[e + 1];
        int s2 = csr_src[e + 2];
        int s3 = csr_src[e + 3];
        int s4 = csr_src[e + 4];
        int s5 = csr_src[e + 5];
        half8 v0 = *(const half8*)(xp + (size_t)s0 * D);
        half8 v1 = *(const half8*)(xp + (size_t)s1 * D);
        half8 v2 = *(const half8*)(xp + (size_t)s2 * D);
        half8 v3 = *(const half8*)(xp + (size_t)s3 * D);
        half8 v4 = *(const half8*)(xp + (size_t)s4 * D);
        half8 v5 = *(const half8*)(xp + (size_t)s5 * D);
#pragma unroll
        for (int k = 0; k < 8; ++k) {
            a[k]  += (float)v0[k] + (float)v2[k] + (float)v4[k];
            b2[k] += (float)v1[k] + (float)v3[k] + (float)v5[k];
        }
    }
    for (; e < e1; ++e) {
        int s0 = csr_src[e];
        half8 v0 = *(const half8*)(xp + (size_t)s0 * D);
#pragma unroll
        for (int k = 0; k < 8; ++k) a[k] += (float)v0[k];
    }

    float t = T[wid];
    float dn = dst_norm[wid];
    const float invN = 1.0f / (float)N;
    half8 o;
#pragma unroll
    for (int k = 0; k < 8; ++k) {
        int c = c0 + k;
        float mu = stats[c] * invN;
        float var = stats[D + c] * invN - mu * mu;
        float sc = gamma[c] * rsqrtf(var + EPS);
        float sh = beta[c] - mu * sc;
        o[k] = (_Float16)(dn * (sc * (a[k] + b2[k]) + sh * t));
    }
    *(half8*)(agg + (size_t)wid * D + c0) = o;
}

// ---------------------------------------------------------------------------
// C = relu(A @ W + bias) via f16 MFMA with global_load_lds staging.
// (round-1 verified structure: 128x128 tile, BK=32, 4 waves)
// STATS variant pre-scales the stored f16 value by src_norm[row] (stats
// accumulate the RAW value) so the next layer's aggregate needs no norm loads.
// ---------------------------------------------------------------------------
template <typename OutT, bool STATS>
__global__ __launch_bounds__(256) void mm_f16_relu(
    const _Float16* __restrict__ A, const _Float16* __restrict__ Bt,
    const float* __restrict__ bias, OutT* __restrict__ C, int M,
    float* __restrict__ stats, const float* __restrict__ src_norm) {
    __shared__ __align__(16) _Float16 As[128 * 32];
    __shared__ __align__(16) _Float16 Bs[128 * 32];
    const int tid  = threadIdx.x;
    const int wave = tid >> 6;
    const int lane = tid & 63;
    const int quad = lane >> 4;
    const int l16  = lane & 15;
    const int row0 = blockIdx.x * 128;
    const int col0 = blockIdx.y * 128;
    const int wm = (wave & 1) * 64;
    const int wn = (wave >> 1) * 64;
    const int sr = lane >> 2;
    const int sc = (lane & 3) * 8;

    int ar0 = row0 + wave * 32 + sr;
    int ar1 = ar0 + 16;
    if (ar0 >= M) ar0 = M - 1;
    if (ar1 >= M) ar1 = M - 1;
    const _Float16* gA0 = A + (size_t)ar0 * D + sc;
    const _Float16* gA1 = A + (size_t)ar1 * D + sc;
    const _Float16* gB0 = Bt + (size_t)(col0 + wave * 32 + sr) * D + sc;
    const _Float16* gB1 = Bt + (size_t)(col0 + wave * 32 + 16 + sr) * D + sc;
    _Float16* lA0 = As + (wave * 32) * 32;
    _Float16* lA1 = As + (wave * 32 + 16) * 32;
    _Float16* lB0 = Bs + (wave * 32) * 32;
    _Float16* lB1 = Bs + (wave * 32 + 16) * 32;

    floatx4 acc[4][4] = {};

    for (int k0 = 0; k0 < D; k0 += 32) {
        __syncthreads();
        glds16(gA0 + k0, lA0);
        glds16(gA1 + k0, lA1);
        glds16(gB0 + k0, lB0);
        glds16(gB1 + k0, lB1);
        __syncthreads();  // compiler inserts vmcnt(0) drain here
        half8 af[4], bf[4];
        for (int i = 0; i < 4; ++i)
            af[i] = *(const half8*)(As + (wm + i * 16 + l16) * 32 + quad * 8);
        for (int j = 0; j < 4; ++j)
            bf[j] = *(const half8*)(Bs + (wn + j * 16 + l16) * 32 + quad * 8);
        for (int i = 0; i < 4; ++i)
            for (int j = 0; j < 4; ++j)
                acc[i][j] = __builtin_amdgcn_mfma_f32_16x16x32_f16(
                    af[i], bf[j], acc[i][j], 0, 0, 0);
    }

    // epilogue: C/D layout col = lane&15, row = quad*4 + reg
    float s[4] = {}, q[4] = {};
    for (int i = 0; i < 4; ++i) {
        for (int r = 0; r < 4; ++r) {
            int row = row0 + wm + i * 16 + quad * 4 + r;
            bool valid = row < M;
            float sn = 1.0f;
            if (STATS && valid) sn = src_norm[row];
            for (int j = 0; j < 4; ++j) {
                int col = col0 + wn + j * 16 + l16;
                float v = acc[i][j][r] + bias[col];
                v = v > 0.f ? v : 0.f;
                if (valid) {
                    if (STATS) {
                        C[(size_t)row * D + col] = (OutT)(v * sn);
                        s[j] += v; q[j] += v * v;
                    } else {
                        C[(size_t)row * D + col] = (OutT)v;
                    }
                }
            }
        }
    }
    if (STATS) {
        for (int j = 0; j < 4; ++j) {
            float sv = s[j], qv = q[j];
            sv += __shfl_xor(sv, 16); sv += __shfl_xor(sv, 32);
            qv += __shfl_xor(qv, 16); qv += __shfl_xor(qv, 32);
            if (quad == 0) {
                int col = col0 + wn + j * 16 + l16;
                atomicAdd(&stats[col], sv);
                atomicAdd(&stats[D + col], qv);
            }
        }
    }
}

// ---------------------------------------------------------------------------
extern "C" void kernel_launch(void* const* d_in, const int* in_sizes, int n_in,
                              void* d_out, int out_size, void* d_ws, size_t ws_size,
                              hipStream_t stream) {
    const float* x_in  = (const float*)d_in[0];
    const int*   src   = (const int*)d_in[1];
    const int*   dst   = (const int*)d_in[2];
    const float* gamma = (const float*)d_in[3];
    const float* beta  = (const float*)d_in[4];
    const float* W     = (const float*)d_in[5];
    const float* b     = (const float*)d_in[6];
    float* out = (float*)d_out;

    // workspace carve-up (16B-aligned segments first)
    char* p = (char*)d_ws;
    _Float16* x16 = (_Float16*)p;  p += (size_t)N * D * 2;       // 10.24 MB
    _Float16* agg = (_Float16*)p;  p += (size_t)N * D * 2;       // 10.24 MB
    _Float16* Wt  = (_Float16*)p;  p += (size_t)L * D * D * 2;   // 1.57 MB
    float* src_norm = (float*)p;   p += (size_t)N * 4;
    float* dst_norm = (float*)p;   p += (size_t)N * 4;
    // contiguous zero-init region: out_deg, in_deg, stats0..2, T
    int* out_deg   = (int*)p;      p += (size_t)N * 4;
    int* in_deg    = (int*)p;      p += (size_t)N * 4;
    float* stats0  = (float*)p;    p += 2 * D * 4;
    float* stats1  = (float*)p;    p += 2 * D * 4;
    float* stats2  = (float*)p;    p += 2 * D * 4;
    float* T       = (float*)p;    p += (size_t)N * 4;
    int* csr_off   = (int*)p;      p += (size_t)(N + 1) * 4;
    int* cursor    = (int*)p;      p += (size_t)N * 4;
    int* csr_src   = (int*)p;      p += (size_t)E * 4;

    float* stats_in[3] = {stats0, stats1, stats2};

    // --- setup ---
    hipMemsetAsync(out_deg, 0, (3 * (size_t)N + 6 * D) * sizeof(int), stream);
    mega_setup<<<MEGA_BLOCKS, 256, 0, stream>>>(src, dst, x_in, W,
                                                out_deg, in_deg, stats0, Wt);
    scan_indeg<<<1, 1024, 0, stream>>>(in_deg, out_deg, csr_off, cursor,
                                       src_norm, dst_norm);
    csr_fill_conv<<<DEG_BLOCKS + CONV_BLOCKS, 256, 0, stream>>>(
        src, dst, x_in, src_norm, cursor, csr_src, T, x16);

    dim3 mm_grid((N + 127) / 128, D / 128);
    const int agg_blocks = (N + 3) / 4;  // 2500 blocks, 1 wave per node

    for (int l = 0; l < L; ++l) {
        const float* gl  = gamma + (size_t)l * D;
        const float* bl  = beta + (size_t)l * D;
        const _Float16* Wl = Wt + (size_t)l * D * D;
        const float* bil = b + (size_t)l * D;

        aggregate_pre<<<agg_blocks, 256, 0, stream>>>(
            x16, csr_off, csr_src, T, dst_norm, stats_in[l], gl, bl, agg);
        if (l == L - 1) {
            mm_f16_relu<float, false><<<mm_grid, 256, 0, stream>>>(
                agg, Wl, bil, out, N, nullptr, nullptr);
        } else {
            mm_f16_relu<_Float16, true><<<mm_grid, 256, 0, stream>>>(
                agg, Wl, bil, x16, N, stats_in[l + 1], src_norm);
        }
    }
}